// Round 1
// baseline (284.913 us; speedup 1.0000x reference)
//
#include <hip/hip_runtime.h>
#include <cmath>

// K[n,m] = sv^2 * sum_p (x1[n,p]-off)*(x2[m,p]-off) + sb^2,  N=M=8192, P=16.
// Output 256 MiB fp32 -> pure write-BW-bound (~41 us floor at 6.5 TB/s).
//
// Two-pass design:
//  1) prep_kernel: a'[p][n] = sv*(x1[n][p]-off), b'[p][m] = sv*(x2[m][p]-off)
//     written TRANSPOSED into d_ws (2 x 512 KB, L2-resident). Folding sv into
//     both factors makes K = dot(a',b') + sb2.
//  2) gemm_kernel: 128x256 tile / 512 threads (8 waves). Staging uses
//     global_load_lds width-16 (3 wave-instrs, no ds_write, no VALU) --
//     possible only because tiles are pre-transposed [p][row]. Compute reads:
//     a via wave-uniform broadcast ds_read_b128, b via stride-1 ds_read_b128
//     (both conflict-free). Thread = 16 rows x 4 cols; epilogue is 16
//     nontemporal global_store_dwordx4, each wave-instr 1024 B contiguous.

typedef float f32x4 __attribute__((ext_vector_type(4)));

__device__ __forceinline__ void gload_lds16(const float* g, float* l) {
    __builtin_amdgcn_global_load_lds(
        (const __attribute__((address_space(1))) void*)g,
        (__attribute__((address_space(3))) void*)l, 16, 0, 0);
}

// ---- Pass 1: offset-subtract, scale by sv, transpose to [16][rows] ----
__global__ __launch_bounds__(256) void prep_kernel(
    const float* __restrict__ x1, const float* __restrict__ x2,
    const float* __restrict__ p_lsv, const float* __restrict__ p_off,
    float* __restrict__ a_t, float* __restrict__ b_t, int n, int m)
{
    const float off = p_off[0];
    const float sv  = expf(p_lsv[0]);

    int b = blockIdx.x;
    const int nb = n >> 8;                 // blocks covering x1
    const float* src; float* dst; int rows;
    if (b < nb) { src = x1; dst = a_t; rows = n; }
    else        { b -= nb; src = x2; dst = b_t; rows = m; }

    const int r = (b << 8) + threadIdx.x;  // source row
    const f32x4* g = (const f32x4*)(src + (size_t)r * 16);
    float vals[16];
    #pragma unroll
    for (int q = 0; q < 4; ++q) {
        f32x4 v = g[q];
        #pragma unroll
        for (int j = 0; j < 4; ++j) vals[q * 4 + j] = v[j];
    }
    #pragma unroll
    for (int p = 0; p < 16; ++p)           // lanes write contiguous r -> coalesced
        dst[(size_t)p * rows + r] = sv * (vals[p] - off);
}

// ---- Pass 2: rank-16 outer product, write-BW-bound ----
__global__ __launch_bounds__(512, 4) void gemm_kernel(
    const float* __restrict__ a_t, const float* __restrict__ b_t,
    const float* __restrict__ p_lsb, float* __restrict__ out, int n, int m)
{
    __shared__ float s1[16 * 128];   // [p][128] packed, a' tile
    __shared__ float s2[16 * 256];   // [p][256] packed, b' tile

    const int tid  = threadIdx.x;
    const int lane = tid & 63;
    const int wid  = tid >> 6;               // wave 0..7
    const int n0 = blockIdx.y * 128;
    const int m0 = blockIdx.x * 256;

    // Stage: wave wid loads b' rows {wid, wid+8} (1024 B each, 1 instr) and
    // a' row-pair {2wid, 2wid+1} (2 x 512 B in one instr via per-lane gsrc).
    {
        const float* g0 = b_t + (size_t)wid * m + m0 + (lane << 2);
        gload_lds16(g0, &s2[wid * 256]);
        const float* g1 = b_t + (size_t)(wid + 8) * m + m0 + (lane << 2);
        gload_lds16(g1, &s2[(wid + 8) * 256]);
        const int pr = (wid << 1) + (lane >> 5);
        const float* g2 = a_t + (size_t)pr * n + n0 + ((lane & 31) << 2);
        gload_lds16(g2, &s1[(wid << 1) * 128]);
    }

    const float sb  = expf(p_lsb[0]);
    const float sb2 = sb * sb;

    float acc[16][4];
    #pragma unroll
    for (int r = 0; r < 16; ++r)
        #pragma unroll
        for (int c = 0; c < 4; ++c) acc[r][c] = 0.0f;

    __syncthreads();   // compiler drains vmcnt(0) for global_load_lds here

    // Thread output: rows n0 + wid*16 .. +15, cols m0 + lane*4 .. +3.
    #pragma unroll
    for (int p = 0; p < 16; ++p) {
        const f32x4 b4 = *(const f32x4*)&s2[p * 256 + (lane << 2)];  // stride-1
        const float* ap = &s1[p * 128 + (wid << 4)];                 // uniform
        const f32x4 a0 = *(const f32x4*)(ap + 0);
        const f32x4 a1 = *(const f32x4*)(ap + 4);
        const f32x4 a2 = *(const f32x4*)(ap + 8);
        const f32x4 a3 = *(const f32x4*)(ap + 12);
        float av[16];
        #pragma unroll
        for (int j = 0; j < 4; ++j) {
            av[j]      = a0[j];
            av[4 + j]  = a1[j];
            av[8 + j]  = a2[j];
            av[12 + j] = a3[j];
        }
        #pragma unroll
        for (int r = 0; r < 16; ++r)
            #pragma unroll
            for (int c = 0; c < 4; ++c)
                acc[r][c] += av[r] * b4[c];
    }

    // Epilogue: 16 nontemporal dwordx4 stores; each wave-instr = 1024 B contiguous.
    float* op = out + (size_t)(n0 + (wid << 4)) * m + m0 + (lane << 2);
    #pragma unroll
    for (int r = 0; r < 16; ++r) {
        f32x4 o;
        o[0] = acc[r][0] + sb2;
        o[1] = acc[r][1] + sb2;
        o[2] = acc[r][2] + sb2;
        o[3] = acc[r][3] + sb2;
        __builtin_nontemporal_store(o, (f32x4*)op);
        op += m;
    }
}

extern "C" void kernel_launch(void* const* d_in, const int* in_sizes, int n_in,
                              void* d_out, int out_size, void* d_ws, size_t ws_size,
                              hipStream_t stream) {
    const float* x1  = (const float*)d_in[0];
    const float* x2  = (const float*)d_in[1];
    const float* lsb = (const float*)d_in[2];
    const float* lsv = (const float*)d_in[3];
    const float* off = (const float*)d_in[4];
    float* out = (float*)d_out;

    const int n = in_sizes[0] / 16;   // 8192
    const int m = in_sizes[1] / 16;   // 8192

    float* a_t = (float*)d_ws;                    // [16][n]  512 KB
    float* b_t = a_t + (size_t)16 * n;            // [16][m]  512 KB

    prep_kernel<<<dim3((n + m) / 256), 256, 0, stream>>>(x1, x2, lsv, off,
                                                         a_t, b_t, n, m);
    gemm_kernel<<<dim3(m / 256, n / 128), 512, 0, stream>>>(a_t, b_t, lsb,
                                                            out, n, m);
}